// Round 3
// baseline (202.797 us; speedup 1.0000x reference)
//
#include <hip/hip_runtime.h>

typedef short short4s __attribute__((ext_vector_type(4)));
typedef short short8 __attribute__((ext_vector_type(8)));
typedef __bf16 bf16x8 __attribute__((ext_vector_type(8)));
typedef float f32x4 __attribute__((ext_vector_type(4)));

#define NFEAT 1024
#define HDIM  64
#define NHEAD 16
#define TC2   2048
#define QSCL  0.18033688011112043f   // log2(e)/8 folded into Q

__device__ __forceinline__ short f2bf(float f) {
    unsigned int u = __builtin_bit_cast(unsigned int, f);
    u += 0x7fffu + ((u >> 16) & 1u);
    return (short)(u >> 16);
}
__device__ __forceinline__ short f2bfq(float f) {   // let compiler emit v_cvt_pk_bf16_f32
    __bf16 h = (__bf16)f;
    return __builtin_bit_cast(short, h);
}

__device__ __forceinline__ f32x4 mfma_bf16(short8 a, short8 b, f32x4 c) {
    return __builtin_amdgcn_mfma_f32_16x16x32_bf16(
        __builtin_bit_cast(bf16x8, a), __builtin_bit_cast(bf16x8, b), c, 0, 0, 0);
}

#define GLOAD16(gp, lp) __builtin_amdgcn_global_load_lds( \
    (const __attribute__((address_space(1))) void*)(gp),  \
    (__attribute__((address_space(3))) void*)(lp), 16, 0, 0)

// ---------------------------------------------------------------------------
// prep: fp32->bf16 of q/k/v inputs + 4 weights, cache copy + bf16 K/V^T sides.
// ---------------------------------------------------------------------------
__global__ __launch_bounds__(256) void prep_kernel(
    const float* __restrict__ q, const float* __restrict__ k, const float* __restrict__ v,
    const float* __restrict__ Wq, const float* __restrict__ Wk,
    const float* __restrict__ Wv, const float* __restrict__ Wo,
    const float4* __restrict__ cache4,
    short* __restrict__ qin, short* __restrict__ kin, short* __restrict__ vin,
    short* __restrict__ wqb, short* __restrict__ wkb, short* __restrict__ wvb,
    short* __restrict__ wob,
    float4* __restrict__ nc4, short* __restrict__ kbb, short* __restrict__ vtb)
{
    const int b = blockIdx.x, tid = threadIdx.x;
    if (b < 5120) {
        const float* src; short* dst; size_t base;
        if (b < 1024)      { src = q;  dst = qin; base = (size_t)b * 2048; }
        else if (b < 2048) { src = k;  dst = kin; base = (size_t)(b - 1024) * 2048; }
        else if (b < 3072) { src = v;  dst = vin; base = (size_t)(b - 2048) * 2048; }
        else if (b < 3584) { src = Wq; dst = wqb; base = (size_t)(b - 3072) * 2048; }
        else if (b < 4096) { src = Wk; dst = wkb; base = (size_t)(b - 3584) * 2048; }
        else if (b < 4608) { src = Wv; dst = wvb; base = (size_t)(b - 4096) * 2048; }
        else               { src = Wo; dst = wob; base = (size_t)(b - 4608) * 2048; }
        size_t i = base + (size_t)tid * 8;
        float4 a0 = *(const float4*)(src + i);
        float4 a1 = *(const float4*)(src + i + 4);
        short8 o;
        o[0] = f2bf(a0.x); o[1] = f2bf(a0.y); o[2] = f2bf(a0.z); o[3] = f2bf(a0.w);
        o[4] = f2bf(a1.x); o[5] = f2bf(a1.y); o[6] = f2bf(a1.z); o[7] = f2bf(a1.w);
        *(short8*)(dst + i) = o;
    } else {
        int i = (b - 5120) * 256 + tid;           // over 2*16*1024*32 float4
        int c4 = i & 31;
        int t  = (i >> 5) & 1023;
        int bh = i >> 15;
        float4 val = cache4[i];
        nc4[((size_t)bh * TC2 + t) * 32 + c4] = val;
        int c = c4 * 4;
        if (c < 64) {
            size_t base = ((size_t)bh * TC2 + t) * HDIM + c;
            kbb[base + 0] = f2bf(val.x); kbb[base + 1] = f2bf(val.y);
            kbb[base + 2] = f2bf(val.z); kbb[base + 3] = f2bf(val.w);
        } else {
            int d = c - 64;
            size_t base = ((size_t)bh * HDIM + d) * TC2 + t;
            vtb[base + 0 * TC2] = f2bf(val.x); vtb[base + 1 * TC2] = f2bf(val.y);
            vtb[base + 2 * TC2] = f2bf(val.z); vtb[base + 3 * TC2] = f2bf(val.w);
        }
    }
}

// ---------------------------------------------------------------------------
// 128x128 GEMM, BK=64, global_load_lds staging (unchanged from R2).
// ---------------------------------------------------------------------------
__global__ __launch_bounds__(256) void gemm128(
    const short* __restrict__ A0, const short* __restrict__ A1, const short* __restrict__ A2,
    const short* __restrict__ W0, const short* __restrict__ W1, const short* __restrict__ W2,
    const float* __restrict__ b0, const float* __restrict__ b1, const float* __restrict__ b2,
    float* __restrict__ outf, short* __restrict__ qbuf,
    short* __restrict__ kbb, short* __restrict__ vtb, int base_mode)
{
    __shared__ short As[128 * 64];
    __shared__ short Bs[128 * 64];

    int mode;
    const short *A, *W;
    const float* bias;
    if (base_mode == 3) { mode = 3; A = A0; W = W0; bias = b0; }
    else {
        mode = blockIdx.z;
        if (mode == 0)      { A = A0; W = W0; bias = b0; }
        else if (mode == 1) { A = A1; W = W1; bias = b1; }
        else                { A = A2; W = W2; bias = b2; }
    }

    const int tid = threadIdx.x, lane = tid & 63, w = tid >> 6;
    const int wr = w >> 1, wc = w & 1;
    const int lr = lane & 15, lg = lane >> 4;
    const int bx = blockIdx.x, by = blockIdx.y;

    f32x4 acc[4][4];
#pragma unroll
    for (int m = 0; m < 4; ++m)
#pragma unroll
        for (int n = 0; n < 4; ++n) acc[m][n] = (f32x4){0.f, 0.f, 0.f, 0.f};

    const short* agBase = A + (size_t)(by * 128 + w * 32 + (lane >> 3)) * 1024 + (lane & 7) * 8;
    const short* bgBase = W + (size_t)(bx * 128 + w * 32 + (lane >> 3)) * 1024 + (lane & 7) * 8;
    short* asW = &As[w * 2048];
    short* bsW = &Bs[w * 2048];

    for (int kt = 0; kt < 16; ++kt) {
        const short* ag = agBase + kt * 64;
        const short* bg = bgBase + kt * 64;
        GLOAD16(ag,          asW);
        GLOAD16(ag + 8192,   asW + 512);
        GLOAD16(ag + 16384,  asW + 1024);
        GLOAD16(ag + 24576,  asW + 1536);
        GLOAD16(bg,          bsW);
        GLOAD16(bg + 8192,   bsW + 512);
        GLOAD16(bg + 16384,  bsW + 1024);
        GLOAD16(bg + 24576,  bsW + 1536);
        __syncthreads();
#pragma unroll
        for (int kk = 0; kk < 2; ++kk) {
            short8 af[4], bf[4];
#pragma unroll
            for (int m = 0; m < 4; ++m)
                af[m] = *(const short8*)&As[(wr * 64 + m * 16 + lr) * 64 + kk * 32 + lg * 8];
#pragma unroll
            for (int n = 0; n < 4; ++n)
                bf[n] = *(const short8*)&Bs[(wc * 64 + n * 16 + lr) * 64 + kk * 32 + lg * 8];
#pragma unroll
            for (int m = 0; m < 4; ++m)
#pragma unroll
                for (int n = 0; n < 4; ++n)
                    acc[m][n] = mfma_bf16(af[m], bf[n], acc[m][n]);
        }
        __syncthreads();
    }

#pragma unroll
    for (int m = 0; m < 4; ++m) {
#pragma unroll
        for (int n = 0; n < 4; ++n) {
            const int cg = bx * 128 + wc * 64 + n * 16 + lr;
            const int rg0 = by * 128 + wr * 64 + m * 16 + lg * 4;
            const float bv = bias[cg];
            if (mode == 3) {
#pragma unroll
                for (int r = 0; r < 4; ++r)
                    outf[(size_t)(rg0 + r) * NFEAT + cg] = acc[m][n][r] + bv;
            } else {
                const int b = rg0 >> 10, t0 = rg0 & 1023;
                const int h = cg >> 6, d = cg & 63;
                const size_t bh = (size_t)b * NHEAD + h;
                if (mode == 0) {
#pragma unroll
                    for (int r = 0; r < 4; ++r)
                        qbuf[(bh * 1024 + t0 + r) * HDIM + d] = f2bf((acc[m][n][r] + bv) * QSCL);
                } else if (mode == 1) {
#pragma unroll
                    for (int r = 0; r < 4; ++r) {
                        float val = acc[m][n][r] + bv;
                        outf[(bh * TC2 + 1024 + t0 + r) * 128 + d] = val;
                        kbb[(bh * TC2 + 1024 + t0 + r) * HDIM + d] = f2bf(val);
                    }
                } else {
                    short4s pk;
#pragma unroll
                    for (int r = 0; r < 4; ++r) {
                        float val = acc[m][n][r] + bv;
                        outf[(bh * TC2 + 1024 + t0 + r) * 128 + 64 + d] = val;
                        pk[r] = f2bf(val);
                    }
                    *(short4s*)&vtb[(bh * HDIM + d) * TC2 + 1024 + t0] = pk;
                }
            }
        }
    }
}

// ---------------------------------------------------------------------------
// Flash attention v3: swapped QK^T (lane owns one q-row), no K/V LDS (L2-served
// direct fragment loads), KV-split 2 with f32 partials, defer-max (THR=8 log2).
// Grid: 1024 = xcd(8) x qt(16) x ghi(8); g = ghi*8+xcd -> bh = g>>1, half = g&1.
// 4 waves/block, wave = 16 q-rows. No block-wide barriers at all.
// ---------------------------------------------------------------------------
#define PST 72
__global__ __launch_bounds__(256) void attn_kernel(
    const short* __restrict__ qb, const short* __restrict__ kb,
    const short* __restrict__ vtb, float* __restrict__ opart, float* __restrict__ mlbuf)
{
    __shared__ short Ps[4 * 16 * PST];

    const int tid = threadIdx.x, lane = tid & 63, w = tid >> 6;
    const int lr = lane & 15, lg = lane >> 4;
    const int b0 = blockIdx.x;
    const int xcd = b0 & 7, rest = b0 >> 3;
    const int qt = rest & 15, ghi = rest >> 4;
    const int g = ghi * 8 + xcd;
    const int bh = g >> 1, half = g & 1;

    // Q fragment (B operand): q-row = lr (within wave's 16 rows)
    const short* qrow = qb + ((size_t)bh * 1024 + qt * 64 + w * 16 + lr) * HDIM + lg * 8;
    const short8 bq0 = *(const short8*)(qrow);
    const short8 bq1 = *(const short8*)(qrow + 32);

    const short* kbase = kb  + ((size_t)bh * TC2 + half * 1024 + lr) * HDIM + lg * 8;
    const short* vbase = vtb + ((size_t)bh * HDIM + lr) * TC2 + half * 1024 + lg * 8;

    f32x4 accx[4];
#pragma unroll
    for (int i = 0; i < 4; ++i) accx[i] = (f32x4){0.f, 0.f, 0.f, 0.f};
    float ms = -3.0e38f, ls = 0.f;
    short* pw = &Ps[w * 16 * PST];

    for (int kvt = 0; kvt < 16; ++kvt) {
        const short* kp = kbase + kvt * 64 * HDIM;
        const short* vp = vbase + kvt * 64;

        // ---- S^T = K Q^T  (lane: q-row = lr; kv = 16n + 4lg + r) ----
        f32x4 s[4];
#pragma unroll
        for (int n = 0; n < 4; ++n) {
            short8 k0 = *(const short8*)(kp + n * 1024);
            short8 k1 = *(const short8*)(kp + n * 1024 + 32);
            s[n] = (f32x4){0.f, 0.f, 0.f, 0.f};
            s[n] = mfma_bf16(k0, bq0, s[n]);
            s[n] = mfma_bf16(k1, bq1, s[n]);
        }

        // ---- row max (in-register tree + 2 shuffles) ----
        float v8[8];
#pragma unroll
        for (int i = 0; i < 8; ++i) v8[i] = fmaxf(s[i >> 1][(i & 1) * 2], s[i >> 1][(i & 1) * 2 + 1]);
        float v4a = fmaxf(v8[0], v8[1]), v4b = fmaxf(v8[2], v8[3]);
        float v4c = fmaxf(v8[4], v8[5]), v4d = fmaxf(v8[6], v8[7]);
        float pmax = fmaxf(fmaxf(v4a, v4b), fmaxf(v4c, v4d));
        pmax = fmaxf(pmax, __shfl_xor(pmax, 16));
        pmax = fmaxf(pmax, __shfl_xor(pmax, 32));

        // ---- defer-max rescale (T13) ----
        if (!__all(pmax - ms <= 8.0f)) {
            float mn = fmaxf(ms, pmax);
            float alpha = __builtin_amdgcn_exp2f(ms - mn);
            ms = mn;
            ls *= alpha;
            float ar[4];
#pragma unroll
            for (int r = 0; r < 4; ++r) ar[r] = __shfl(alpha, lg * 4 + r);
#pragma unroll
            for (int nd = 0; nd < 4; ++nd)
#pragma unroll
                for (int r = 0; r < 4; ++r) accx[nd][r] *= ar[r];
        }

        // ---- P = exp2(S - m), row sum ----
        float p[4][4];
        float sm[8];
#pragma unroll
        for (int n = 0; n < 4; ++n) {
#pragma unroll
            for (int r = 0; r < 4; ++r) p[n][r] = __builtin_amdgcn_exp2f(s[n][r] - ms);
        }
#pragma unroll
        for (int i = 0; i < 8; ++i) sm[i] = p[i >> 1][(i & 1) * 2] + p[i >> 1][(i & 1) * 2 + 1];
        float rs = ((sm[0] + sm[1]) + (sm[2] + sm[3])) + ((sm[4] + sm[5]) + (sm[6] + sm[7]));
        rs += __shfl_xor(rs, 16);
        rs += __shfl_xor(rs, 32);
        ls += rs;

        // ---- pack P -> wave-private LDS ----
#pragma unroll
        for (int n = 0; n < 4; ++n) {
            short4s pk;
            pk[0] = f2bfq(p[n][0]); pk[1] = f2bfq(p[n][1]);
            pk[2] = f2bfq(p[n][2]); pk[3] = f2bfq(p[n][3]);
            *(short4s*)&pw[lr * PST + 16 * n + 4 * lg] = pk;
        }

        // ---- PV: O += P V  (V^T fragments direct from global) ----
#pragma unroll
        for (int ks = 0; ks < 2; ++ks) {
            short8 ap = *(const short8*)&pw[lr * PST + ks * 32 + lg * 8];
#pragma unroll
            for (int nd = 0; nd < 4; ++nd) {
                short8 vf = *(const short8*)(vp + nd * 16 * TC2 + ks * 32);
                accx[nd] = mfma_bf16(ap, vf, accx[nd]);
            }
        }
    }

    // ---- epilogue: f32 partials + (m,l) ----
    const size_t rbase = (size_t)half * 32768 + (size_t)bh * 1024 + qt * 64 + w * 16;
#pragma unroll
    for (int nd = 0; nd < 4; ++nd)
#pragma unroll
        for (int r = 0; r < 4; ++r)
            opart[(rbase + lg * 4 + r) * 64 + nd * 16 + lr] = accx[nd][r];
    if (lg == 0) {
        mlbuf[(rbase + lr) * 2]     = ms;
        mlbuf[(rbase + lr) * 2 + 1] = ls;
    }
}

// ---------------------------------------------------------------------------
// Combine the two kv-halves: out = (O1*2^(m1-M) + O2*2^(m2-M)) / l  -> bf16 xb
// ---------------------------------------------------------------------------
__global__ __launch_bounds__(256) void combine_kernel(
    const float* __restrict__ opart, const float* __restrict__ mlbuf,
    short* __restrict__ xb)
{
    int idx = blockIdx.x * 256 + threadIdx.x;    // 262144 = 32768 rows x 8 segs
    int r = idx >> 3, d8 = (idx & 7) * 8;
    float m1 = mlbuf[r * 2],             l1 = mlbuf[r * 2 + 1];
    float m2 = mlbuf[(32768 + r) * 2],   l2 = mlbuf[(32768 + r) * 2 + 1];
    float M  = fmaxf(m1, m2);
    float w1 = __builtin_amdgcn_exp2f(m1 - M);
    float w2 = __builtin_amdgcn_exp2f(m2 - M);
    float inv = 1.0f / (l1 * w1 + l2 * w2);
    const float* o1 = opart + (size_t)r * 64 + d8;
    const float* o2 = opart + (size_t)(32768 + r) * 64 + d8;
    float4 a0 = *(const float4*)o1, a1 = *(const float4*)(o1 + 4);
    float4 b0 = *(const float4*)o2, b1 = *(const float4*)(o2 + 4);
    short8 o;
    o[0] = f2bfq((a0.x * w1 + b0.x * w2) * inv);
    o[1] = f2bfq((a0.y * w1 + b0.y * w2) * inv);
    o[2] = f2bfq((a0.z * w1 + b0.z * w2) * inv);
    o[3] = f2bfq((a0.w * w1 + b0.w * w2) * inv);
    o[4] = f2bfq((a1.x * w1 + b1.x * w2) * inv);
    o[5] = f2bfq((a1.y * w1 + b1.y * w2) * inv);
    o[6] = f2bfq((a1.z * w1 + b1.z * w2) * inv);
    o[7] = f2bfq((a1.w * w1 + b1.w * w2) * inv);
    int bh = r >> 10, tq = r & 1023;
    int b = bh >> 4, h = bh & 15;
    *(short8*)&xb[((size_t)(b * 1024 + tq)) * NFEAT + h * 64 + d8] = o;
}

// ---------------------------------------------------------------------------
extern "C" void kernel_launch(void* const* d_in, const int* in_sizes, int n_in,
                              void* d_out, int out_size, void* d_ws, size_t ws_size,
                              hipStream_t stream) {
    const float* query = (const float*)d_in[0];
    const float* key   = (const float*)d_in[1];
    const float* value = (const float*)d_in[2];
    const float* cache = (const float*)d_in[3];
    const float* Wq = (const float*)d_in[4];
    const float* bq = (const float*)d_in[5];
    const float* Wk = (const float*)d_in[6];
    const float* bk = (const float*)d_in[7];
    const float* Wv = (const float*)d_in[8];
    const float* bv = (const float*)d_in[9];
    const float* Wo = (const float*)d_in[10];
    const float* bo = (const float*)d_in[11];

    float* out0   = (float*)d_out;
    float* ncache = out0 + (size_t)2 * 1024 * 1024;

    short* qin = (short*)d_ws;                       // 0      (2M shorts)
    short* kin = qin + (size_t)2097152;              // 2M
    short* vin = kin + (size_t)2097152;              // 4M
    short* wqb = vin + (size_t)2097152;              // 6M
    short* wkb = wqb + (size_t)1048576;              // 7M
    short* wvb = wkb + (size_t)1048576;              // 8M
    short* wob = wvb + (size_t)1048576;              // 9M
    short* qbuf = wob + (size_t)1048576;             // 10M (2M)
    short* kbb  = qbuf + (size_t)2097152;            // 12M (4M)
    short* vtb  = kbb  + (size_t)4194304;            // 16M (4M) -> 20M total
    // Overlays (dead regions after QKV GEMM):
    float* opart = (float*)d_ws;                     // 4M floats = shorts [0,8M)
    float* mlbuf = (float*)(qin + (size_t)8388608);  // in wvb region
    short* xb    = qbuf;                             // combine output (Q dead then)

    prep_kernel<<<9216, 256, 0, stream>>>(query, key, value, Wq, Wk, Wv, Wo,
        (const float4*)cache, qin, kin, vin, wqb, wkb, wvb, wob,
        (float4*)ncache, kbb, vtb);

    gemm128<<<dim3(8, 16, 3), 256, 0, stream>>>(qin, kin, vin, wqb, wkb, wvb,
        bq, bk, bv, ncache, qbuf, kbb, vtb, 0);

    attn_kernel<<<1024, 256, 0, stream>>>(qbuf, kbb, vtb, opart, mlbuf);

    combine_kernel<<<1024, 256, 0, stream>>>(opart, mlbuf, xb);

    gemm128<<<dim3(8, 16, 1), 256, 0, stream>>>(xb, nullptr, nullptr, wob, nullptr, nullptr,
        bo, nullptr, nullptr, out0, nullptr, nullptr, nullptr, 3);
}

// Round 4
// 121.433 us; speedup vs baseline: 1.6700x; 1.6700x over previous
//
#include <hip/hip_runtime.h>

typedef short short4s __attribute__((ext_vector_type(4)));
typedef short short8 __attribute__((ext_vector_type(8)));
typedef __bf16 bf16x8 __attribute__((ext_vector_type(8)));
typedef float f32x4 __attribute__((ext_vector_type(4)));

#define NFEAT 1024
#define HDIM  64
#define NHEAD 16
#define TC2   2048
#define QSCL  0.18033688011112043f   // log2(e)/8 folded into Q

__device__ __forceinline__ short f2bf(float f) {
    unsigned int u = __builtin_bit_cast(unsigned int, f);
    u += 0x7fffu + ((u >> 16) & 1u);
    return (short)(u >> 16);
}
__device__ __forceinline__ short f2bfq(float f) {
    __bf16 h = (__bf16)f;
    return __builtin_bit_cast(short, h);
}

__device__ __forceinline__ f32x4 mfma_bf16(short8 a, short8 b, f32x4 c) {
    return __builtin_amdgcn_mfma_f32_16x16x32_bf16(
        __builtin_bit_cast(bf16x8, a), __builtin_bit_cast(bf16x8, b), c, 0, 0, 0);
}

#define GLOAD16(gp, lp) __builtin_amdgcn_global_load_lds( \
    (const __attribute__((address_space(1))) void*)(gp),  \
    (__attribute__((address_space(3))) void*)(lp), 16, 0, 0)

// ---------------------------------------------------------------------------
// prep: fp32->bf16 of q/k/v inputs + 4 weights, cache copy + bf16 K/V^T sides.
// ---------------------------------------------------------------------------
__global__ __launch_bounds__(256) void prep_kernel(
    const float* __restrict__ q, const float* __restrict__ k, const float* __restrict__ v,
    const float* __restrict__ Wq, const float* __restrict__ Wk,
    const float* __restrict__ Wv, const float* __restrict__ Wo,
    const float4* __restrict__ cache4,
    short* __restrict__ qin, short* __restrict__ kin, short* __restrict__ vin,
    short* __restrict__ wqb, short* __restrict__ wkb, short* __restrict__ wvb,
    short* __restrict__ wob,
    float4* __restrict__ nc4, short* __restrict__ kbb, short* __restrict__ vtb)
{
    const int b = blockIdx.x, tid = threadIdx.x;
    if (b < 5120) {
        const float* src; short* dst; size_t base;
        if (b < 1024)      { src = q;  dst = qin; base = (size_t)b * 2048; }
        else if (b < 2048) { src = k;  dst = kin; base = (size_t)(b - 1024) * 2048; }
        else if (b < 3072) { src = v;  dst = vin; base = (size_t)(b - 2048) * 2048; }
        else if (b < 3584) { src = Wq; dst = wqb; base = (size_t)(b - 3072) * 2048; }
        else if (b < 4096) { src = Wk; dst = wkb; base = (size_t)(b - 3584) * 2048; }
        else if (b < 4608) { src = Wv; dst = wvb; base = (size_t)(b - 4096) * 2048; }
        else               { src = Wo; dst = wob; base = (size_t)(b - 4608) * 2048; }
        size_t i = base + (size_t)tid * 8;
        float4 a0 = *(const float4*)(src + i);
        float4 a1 = *(const float4*)(src + i + 4);
        short8 o;
        o[0] = f2bf(a0.x); o[1] = f2bf(a0.y); o[2] = f2bf(a0.z); o[3] = f2bf(a0.w);
        o[4] = f2bf(a1.x); o[5] = f2bf(a1.y); o[6] = f2bf(a1.z); o[7] = f2bf(a1.w);
        *(short8*)(dst + i) = o;
    } else {
        int i = (b - 5120) * 256 + tid;           // over 2*16*1024*32 float4
        int c4 = i & 31;
        int t  = (i >> 5) & 1023;
        int bh = i >> 15;
        float4 val = cache4[i];
        nc4[((size_t)bh * TC2 + t) * 32 + c4] = val;
        int c = c4 * 4;
        if (c < 64) {
            size_t base = ((size_t)bh * TC2 + t) * HDIM + c;
            kbb[base + 0] = f2bf(val.x); kbb[base + 1] = f2bf(val.y);
            kbb[base + 2] = f2bf(val.z); kbb[base + 3] = f2bf(val.w);
        } else {
            int d = c - 64;
            size_t base = ((size_t)bh * HDIM + d) * TC2 + t;
            vtb[base + 0 * TC2] = f2bf(val.x); vtb[base + 1 * TC2] = f2bf(val.y);
            vtb[base + 2 * TC2] = f2bf(val.z); vtb[base + 3 * TC2] = f2bf(val.w);
        }
    }
}

// ---------------------------------------------------------------------------
// 128x128 GEMM, BK=64, global_load_lds staging (unchanged).
// ---------------------------------------------------------------------------
__global__ __launch_bounds__(256) void gemm128(
    const short* __restrict__ A0, const short* __restrict__ A1, const short* __restrict__ A2,
    const short* __restrict__ W0, const short* __restrict__ W1, const short* __restrict__ W2,
    const float* __restrict__ b0, const float* __restrict__ b1, const float* __restrict__ b2,
    float* __restrict__ outf, short* __restrict__ qbuf,
    short* __restrict__ kbb, short* __restrict__ vtb, int base_mode)
{
    __shared__ short As[128 * 64];
    __shared__ short Bs[128 * 64];

    int mode;
    const short *A, *W;
    const float* bias;
    if (base_mode == 3) { mode = 3; A = A0; W = W0; bias = b0; }
    else {
        mode = blockIdx.z;
        if (mode == 0)      { A = A0; W = W0; bias = b0; }
        else if (mode == 1) { A = A1; W = W1; bias = b1; }
        else                { A = A2; W = W2; bias = b2; }
    }

    const int tid = threadIdx.x, lane = tid & 63, w = tid >> 6;
    const int wr = w >> 1, wc = w & 1;
    const int lr = lane & 15, lg = lane >> 4;
    const int bx = blockIdx.x, by = blockIdx.y;

    f32x4 acc[4][4];
#pragma unroll
    for (int m = 0; m < 4; ++m)
#pragma unroll
        for (int n = 0; n < 4; ++n) acc[m][n] = (f32x4){0.f, 0.f, 0.f, 0.f};

    const short* agBase = A + (size_t)(by * 128 + w * 32 + (lane >> 3)) * 1024 + (lane & 7) * 8;
    const short* bgBase = W + (size_t)(bx * 128 + w * 32 + (lane >> 3)) * 1024 + (lane & 7) * 8;
    short* asW = &As[w * 2048];
    short* bsW = &Bs[w * 2048];

    for (int kt = 0; kt < 16; ++kt) {
        const short* ag = agBase + kt * 64;
        const short* bg = bgBase + kt * 64;
        GLOAD16(ag,          asW);
        GLOAD16(ag + 8192,   asW + 512);
        GLOAD16(ag + 16384,  asW + 1024);
        GLOAD16(ag + 24576,  asW + 1536);
        GLOAD16(bg,          bsW);
        GLOAD16(bg + 8192,   bsW + 512);
        GLOAD16(bg + 16384,  bsW + 1024);
        GLOAD16(bg + 24576,  bsW + 1536);
        __syncthreads();
#pragma unroll
        for (int kk = 0; kk < 2; ++kk) {
            short8 af[4], bf[4];
#pragma unroll
            for (int m = 0; m < 4; ++m)
                af[m] = *(const short8*)&As[(wr * 64 + m * 16 + lr) * 64 + kk * 32 + lg * 8];
#pragma unroll
            for (int n = 0; n < 4; ++n)
                bf[n] = *(const short8*)&Bs[(wc * 64 + n * 16 + lr) * 64 + kk * 32 + lg * 8];
#pragma unroll
            for (int m = 0; m < 4; ++m)
#pragma unroll
                for (int n = 0; n < 4; ++n)
                    acc[m][n] = mfma_bf16(af[m], bf[n], acc[m][n]);
        }
        __syncthreads();
    }

#pragma unroll
    for (int m = 0; m < 4; ++m) {
#pragma unroll
        for (int n = 0; n < 4; ++n) {
            const int cg = bx * 128 + wc * 64 + n * 16 + lr;
            const int rg0 = by * 128 + wr * 64 + m * 16 + lg * 4;
            const float bv = bias[cg];
            if (mode == 3) {
#pragma unroll
                for (int r = 0; r < 4; ++r)
                    outf[(size_t)(rg0 + r) * NFEAT + cg] = acc[m][n][r] + bv;
            } else {
                const int b = rg0 >> 10, t0 = rg0 & 1023;
                const int h = cg >> 6, d = cg & 63;
                const size_t bh = (size_t)b * NHEAD + h;
                if (mode == 0) {
#pragma unroll
                    for (int r = 0; r < 4; ++r)
                        qbuf[(bh * 1024 + t0 + r) * HDIM + d] = f2bf((acc[m][n][r] + bv) * QSCL);
                } else if (mode == 1) {
#pragma unroll
                    for (int r = 0; r < 4; ++r) {
                        float val = acc[m][n][r] + bv;
                        outf[(bh * TC2 + 1024 + t0 + r) * 128 + d] = val;
                        kbb[(bh * TC2 + 1024 + t0 + r) * HDIM + d] = f2bf(val);
                    }
                } else {
                    short4s pk;
#pragma unroll
                    for (int r = 0; r < 4; ++r) {
                        float val = acc[m][n][r] + bv;
                        outf[(bh * TC2 + 1024 + t0 + r) * 128 + 64 + d] = val;
                        pk[r] = f2bf(val);
                    }
                    *(short4s*)&vtb[(bh * HDIM + d) * TC2 + 1024 + t0] = pk;
                }
            }
        }
    }
}

// ---------------------------------------------------------------------------
// Flash attention v4: swapped QK^T softmax (R3) + async double-buffered LDS
// staging via global_load_lds with XOR-swizzled source (T3-min 2-phase).
// Grid 1024 = xcd(8) x qt(16) x ghi(8); bh = g>>1, half = g&1, KV-split 2.
// LDS: K dbuf 16K + V dbuf 16K + P 8K = 40KB -> 4 blocks/CU.
// ---------------------------------------------------------------------------
__global__ __launch_bounds__(256) void attn_kernel(
    const short* __restrict__ qb, const short* __restrict__ kb,
    const short* __restrict__ vtb, float* __restrict__ opart, float* __restrict__ mlbuf)
{
    __shared__ short Ks[2][64 * 64];
    __shared__ short Vs[2][64 * 64];
    __shared__ short Ps[4][16 * 64];

    const int tid = threadIdx.x, lane = tid & 63, w = tid >> 6;
    const int lr = lane & 15, lg = lane >> 4;
    const int b0 = blockIdx.x;
    const int xcd = b0 & 7, rest = b0 >> 3;
    const int qt = rest & 15, ghi = rest >> 4;
    const int g = ghi * 8 + xcd;
    const int bh = g >> 1, half = g & 1;
    const int xz = lr & 7;

    // Q fragment (B operand): q-row = lr within wave's 16 rows
    const short* qrow = qb + ((size_t)bh * 1024 + qt * 64 + w * 16 + lr) * HDIM + lg * 8;
    const short8 bq0 = *(const short8*)(qrow);
    const short8 bq1 = *(const short8*)(qrow + 32);

    // staging source addresses (pre-swizzled so linear LDS holds swizzled data)
    const int rT = w * 16 + (lane >> 3);          // tile row this lane stages (i=0)
    const int cswz = ((lane & 7) ^ (rT & 7)) * 8; // swizzled short-offset in row
    const short* kgb = kb  + ((size_t)bh * TC2 + half * 1024 + rT) * HDIM + cswz;
    const short* vgb = vtb + ((size_t)bh * HDIM + rT) * TC2 + half * 1024 + cswz;
    short* kdst = &Ks[0][0] + w * 1024;           // wave-uniform base (+8192 for buf1)
    short* vdst = &Vs[0][0] + w * 1024;

#define STAGE(bufsel, kvt_) do {                                         \
        const short* kg_ = kgb + (size_t)(kvt_) * 64 * HDIM;             \
        const short* vg_ = vgb + (kvt_) * 64;                            \
        GLOAD16(kg_,            kdst + (bufsel) * 4096);                 \
        GLOAD16(kg_ + 8 * HDIM, kdst + (bufsel) * 4096 + 512);           \
        GLOAD16(vg_,            vdst + (bufsel) * 4096);                 \
        GLOAD16(vg_ + 8 * TC2,  vdst + (bufsel) * 4096 + 512);           \
    } while (0)

    f32x4 accx[4];
#pragma unroll
    for (int i = 0; i < 4; ++i) accx[i] = (f32x4){0.f, 0.f, 0.f, 0.f};
    float ms = -3.0e38f, ls = 0.f;
    short* pw = &Ps[w][0];

    STAGE(0, 0);
    __syncthreads();

    int cur = 0;
    for (int kvt = 0; kvt < 16; ++kvt) {
        if (kvt < 15) STAGE(cur ^ 1, kvt + 1);
        const short* Kc = &Ks[cur][0];
        const short* Vc = &Vs[cur][0];

        // ---- S^T = K Q^T  (lane: q-row = lr; kv = 16n + 4lg + r) ----
        f32x4 s[4];
#pragma unroll
        for (int n = 0; n < 4; ++n) {
            const short* kt = Kc + (n * 16 + lr) * 64;
            short8 k0 = *(const short8*)&kt[(lg ^ xz) * 8];
            short8 k1 = *(const short8*)&kt[((4 + lg) ^ xz) * 8];
            s[n] = (f32x4){0.f, 0.f, 0.f, 0.f};
            s[n] = mfma_bf16(k0, bq0, s[n]);
            s[n] = mfma_bf16(k1, bq1, s[n]);
        }

        // ---- row max (in-register tree + 2 shuffles) ----
        float v8[8];
#pragma unroll
        for (int i = 0; i < 8; ++i) v8[i] = fmaxf(s[i >> 1][(i & 1) * 2], s[i >> 1][(i & 1) * 2 + 1]);
        float v4a = fmaxf(v8[0], v8[1]), v4b = fmaxf(v8[2], v8[3]);
        float v4c = fmaxf(v8[4], v8[5]), v4d = fmaxf(v8[6], v8[7]);
        float pmax = fmaxf(fmaxf(v4a, v4b), fmaxf(v4c, v4d));
        pmax = fmaxf(pmax, __shfl_xor(pmax, 16));
        pmax = fmaxf(pmax, __shfl_xor(pmax, 32));

        // ---- defer-max rescale (T13) ----
        if (!__all(pmax - ms <= 8.0f)) {
            float mn = fmaxf(ms, pmax);
            float alpha = __builtin_amdgcn_exp2f(ms - mn);
            ms = mn;
            ls *= alpha;
            float ar[4];
#pragma unroll
            for (int r = 0; r < 4; ++r) ar[r] = __shfl(alpha, lg * 4 + r);
#pragma unroll
            for (int nd = 0; nd < 4; ++nd)
#pragma unroll
                for (int r = 0; r < 4; ++r) accx[nd][r] *= ar[r];
        }

        // ---- P = exp2(S - m), row sum ----
        float p[4][4];
        float sm[8];
#pragma unroll
        for (int n = 0; n < 4; ++n)
#pragma unroll
            for (int r = 0; r < 4; ++r) p[n][r] = __builtin_amdgcn_exp2f(s[n][r] - ms);
#pragma unroll
        for (int i = 0; i < 8; ++i) sm[i] = p[i >> 1][(i & 1) * 2] + p[i >> 1][(i & 1) * 2 + 1];
        float rs = ((sm[0] + sm[1]) + (sm[2] + sm[3])) + ((sm[4] + sm[5]) + (sm[6] + sm[7]));
        rs += __shfl_xor(rs, 16);
        rs += __shfl_xor(rs, 32);
        ls += rs;

        // ---- pack P -> wave-private swizzled LDS [16 q-rows][64 kv] ----
#pragma unroll
        for (int n = 0; n < 4; ++n) {
            short4s pk;
            pk[0] = f2bfq(p[n][0]); pk[1] = f2bfq(p[n][1]);
            pk[2] = f2bfq(p[n][2]); pk[3] = f2bfq(p[n][3]);
            int slot = (2 * n + (lg >> 1)) ^ xz;
            *(short4s*)&pw[lr * 64 + slot * 8 + (lg & 1) * 4] = pk;
        }

        // ---- PV: O += P V ----
        short8 ap0 = *(const short8*)&pw[lr * 64 + (lg ^ xz) * 8];
        short8 ap1 = *(const short8*)&pw[lr * 64 + ((4 + lg) ^ xz) * 8];
#pragma unroll
        for (int nd = 0; nd < 4; ++nd) {
            const short* vt = Vc + (nd * 16 + lr) * 64;
            short8 vf0 = *(const short8*)&vt[(lg ^ xz) * 8];
            short8 vf1 = *(const short8*)&vt[((4 + lg) ^ xz) * 8];
            accx[nd] = mfma_bf16(ap0, vf0, accx[nd]);
            accx[nd] = mfma_bf16(ap1, vf1, accx[nd]);
        }

        __syncthreads();     // implicit vmcnt(0): next tile staged; buf reuse safe
        cur ^= 1;
    }

    // ---- epilogue: f32 partials + (m,l) ----
    const size_t rbase = (size_t)half * 32768 + (size_t)bh * 1024 + qt * 64 + w * 16;
#pragma unroll
    for (int nd = 0; nd < 4; ++nd)
#pragma unroll
        for (int r = 0; r < 4; ++r)
            opart[(rbase + lg * 4 + r) * 64 + nd * 16 + lr] = accx[nd][r];
    if (lg == 0) {
        mlbuf[(rbase + lr) * 2]     = ms;
        mlbuf[(rbase + lr) * 2 + 1] = ls;
    }
#undef STAGE
}

// ---------------------------------------------------------------------------
// Combine the two kv-halves: out = (O1*2^(m1-M) + O2*2^(m2-M)) / l  -> bf16 xb
// ---------------------------------------------------------------------------
__global__ __launch_bounds__(256) void combine_kernel(
    const float* __restrict__ opart, const float* __restrict__ mlbuf,
    short* __restrict__ xb)
{
    int idx = blockIdx.x * 256 + threadIdx.x;    // 262144 = 32768 rows x 8 segs
    int r = idx >> 3, d8 = (idx & 7) * 8;
    float m1 = mlbuf[r * 2],             l1 = mlbuf[r * 2 + 1];
    float m2 = mlbuf[(32768 + r) * 2],   l2 = mlbuf[(32768 + r) * 2 + 1];
    float M  = fmaxf(m1, m2);
    float w1 = __builtin_amdgcn_exp2f(m1 - M);
    float w2 = __builtin_amdgcn_exp2f(m2 - M);
    float inv = 1.0f / (l1 * w1 + l2 * w2);
    const float* o1 = opart + (size_t)r * 64 + d8;
    const float* o2 = opart + (size_t)(32768 + r) * 64 + d8;
    float4 a0 = *(const float4*)o1, a1 = *(const float4*)(o1 + 4);
    float4 b0 = *(const float4*)o2, b1 = *(const float4*)(o2 + 4);
    short8 o;
    o[0] = f2bfq((a0.x * w1 + b0.x * w2) * inv);
    o[1] = f2bfq((a0.y * w1 + b0.y * w2) * inv);
    o[2] = f2bfq((a0.z * w1 + b0.z * w2) * inv);
    o[3] = f2bfq((a0.w * w1 + b0.w * w2) * inv);
    o[4] = f2bfq((a1.x * w1 + b1.x * w2) * inv);
    o[5] = f2bfq((a1.y * w1 + b1.y * w2) * inv);
    o[6] = f2bfq((a1.z * w1 + b1.z * w2) * inv);
    o[7] = f2bfq((a1.w * w1 + b1.w * w2) * inv);
    int bh = r >> 10, tq = r & 1023;
    int b = bh >> 4, h = bh & 15;
    *(short8*)&xb[((size_t)(b * 1024 + tq)) * NFEAT + h * 64 + d8] = o;
}

// ---------------------------------------------------------------------------
extern "C" void kernel_launch(void* const* d_in, const int* in_sizes, int n_in,
                              void* d_out, int out_size, void* d_ws, size_t ws_size,
                              hipStream_t stream) {
    const float* query = (const float*)d_in[0];
    const float* key   = (const float*)d_in[1];
    const float* value = (const float*)d_in[2];
    const float* cache = (const float*)d_in[3];
    const float* Wq = (const float*)d_in[4];
    const float* bq = (const float*)d_in[5];
    const float* Wk = (const float*)d_in[6];
    const float* bk = (const float*)d_in[7];
    const float* Wv = (const float*)d_in[8];
    const float* bv = (const float*)d_in[9];
    const float* Wo = (const float*)d_in[10];
    const float* bo = (const float*)d_in[11];

    float* out0   = (float*)d_out;
    float* ncache = out0 + (size_t)2 * 1024 * 1024;

    short* qin = (short*)d_ws;                       // 0      (2M shorts)
    short* kin = qin + (size_t)2097152;              // 2M
    short* vin = kin + (size_t)2097152;              // 4M
    short* wqb = vin + (size_t)2097152;              // 6M
    short* wkb = wqb + (size_t)1048576;              // 7M
    short* wvb = wkb + (size_t)1048576;              // 8M
    short* wob = wvb + (size_t)1048576;              // 9M
    short* qbuf = wob + (size_t)1048576;             // 10M (2M)
    short* kbb  = qbuf + (size_t)2097152;            // 12M (4M)
    short* vtb  = kbb  + (size_t)4194304;            // 16M (4M) -> 20M total
    // Overlays (dead regions after QKV GEMM):
    float* opart = (float*)d_ws;                     // 4M floats = shorts [0,8M)
    float* mlbuf = (float*)(qin + (size_t)8388608);  // in wvb region
    short* xb    = qbuf;                             // combine output (Q dead then)

    prep_kernel<<<9216, 256, 0, stream>>>(query, key, value, Wq, Wk, Wv, Wo,
        (const float4*)cache, qin, kin, vin, wqb, wkb, wvb, wob,
        (float4*)ncache, kbb, vtb);

    gemm128<<<dim3(8, 16, 3), 256, 0, stream>>>(qin, kin, vin, wqb, wkb, wvb,
        bq, bk, bv, ncache, qbuf, kbb, vtb, 0);

    attn_kernel<<<1024, 256, 0, stream>>>(qbuf, kbb, vtb, opart, mlbuf);

    combine_kernel<<<1024, 256, 0, stream>>>(opart, mlbuf, xb);

    gemm128<<<dim3(8, 16, 1), 256, 0, stream>>>(xb, nullptr, nullptr, wob, nullptr, nullptr,
        bo, nullptr, nullptr, out0, nullptr, nullptr, nullptr, 3);
}

// Round 5
// 117.154 us; speedup vs baseline: 1.7310x; 1.0365x over previous
//
#include <hip/hip_runtime.h>

typedef short short4s __attribute__((ext_vector_type(4)));
typedef short short8 __attribute__((ext_vector_type(8)));
typedef __bf16 bf16x8 __attribute__((ext_vector_type(8)));
typedef float f32x4 __attribute__((ext_vector_type(4)));

#define NFEAT 1024
#define HDIM  64
#define NHEAD 16
#define TC2   2048
#define QSCL  0.18033688011112043f   // log2(e)/8 folded into Q

__device__ __forceinline__ short f2bf(float f) {
    unsigned int u = __builtin_bit_cast(unsigned int, f);
    u += 0x7fffu + ((u >> 16) & 1u);
    return (short)(u >> 16);
}
__device__ __forceinline__ short f2bfq(float f) {
    __bf16 h = (__bf16)f;
    return __builtin_bit_cast(short, h);
}
__device__ __forceinline__ float bf2f(short s) {
    unsigned int u = ((unsigned int)(unsigned short)s) << 16;
    return __builtin_bit_cast(float, u);
}

__device__ __forceinline__ f32x4 mfma_bf16(short8 a, short8 b, f32x4 c) {
    return __builtin_amdgcn_mfma_f32_16x16x32_bf16(
        __builtin_bit_cast(bf16x8, a), __builtin_bit_cast(bf16x8, b), c, 0, 0, 0);
}

#define GLOAD16(gp, lp) __builtin_amdgcn_global_load_lds( \
    (const __attribute__((address_space(1))) void*)(gp),  \
    (__attribute__((address_space(3))) void*)(lp), 16, 0, 0)

// ---------------------------------------------------------------------------
// prep: fp32->bf16 of q/k/v inputs + 4 weights, cache copy + bf16 K/V^T sides.
// ---------------------------------------------------------------------------
__global__ __launch_bounds__(256) void prep_kernel(
    const float* __restrict__ q, const float* __restrict__ k, const float* __restrict__ v,
    const float* __restrict__ Wq, const float* __restrict__ Wk,
    const float* __restrict__ Wv, const float* __restrict__ Wo,
    const float4* __restrict__ cache4,
    short* __restrict__ qin, short* __restrict__ kin, short* __restrict__ vin,
    short* __restrict__ wqb, short* __restrict__ wkb, short* __restrict__ wvb,
    short* __restrict__ wob,
    float4* __restrict__ nc4, short* __restrict__ kbb, short* __restrict__ vtb)
{
    const int b = blockIdx.x, tid = threadIdx.x;
    if (b < 5120) {
        const float* src; short* dst; size_t base;
        if (b < 1024)      { src = q;  dst = qin; base = (size_t)b * 2048; }
        else if (b < 2048) { src = k;  dst = kin; base = (size_t)(b - 1024) * 2048; }
        else if (b < 3072) { src = v;  dst = vin; base = (size_t)(b - 2048) * 2048; }
        else if (b < 3584) { src = Wq; dst = wqb; base = (size_t)(b - 3072) * 2048; }
        else if (b < 4096) { src = Wk; dst = wkb; base = (size_t)(b - 3584) * 2048; }
        else if (b < 4608) { src = Wv; dst = wvb; base = (size_t)(b - 4096) * 2048; }
        else               { src = Wo; dst = wob; base = (size_t)(b - 4608) * 2048; }
        size_t i = base + (size_t)tid * 8;
        float4 a0 = *(const float4*)(src + i);
        float4 a1 = *(const float4*)(src + i + 4);
        short8 o;
        o[0] = f2bf(a0.x); o[1] = f2bf(a0.y); o[2] = f2bf(a0.z); o[3] = f2bf(a0.w);
        o[4] = f2bf(a1.x); o[5] = f2bf(a1.y); o[6] = f2bf(a1.z); o[7] = f2bf(a1.w);
        *(short8*)(dst + i) = o;
    } else {
        int i = (b - 5120) * 256 + tid;           // over 2*16*1024*32 float4
        int c4 = i & 31;
        int t  = (i >> 5) & 1023;
        int bh = i >> 15;
        float4 val = cache4[i];
        nc4[((size_t)bh * TC2 + t) * 32 + c4] = val;
        int c = c4 * 4;
        if (c < 64) {
            size_t base = ((size_t)bh * TC2 + t) * HDIM + c;
            kbb[base + 0] = f2bf(val.x); kbb[base + 1] = f2bf(val.y);
            kbb[base + 2] = f2bf(val.z); kbb[base + 3] = f2bf(val.w);
        } else {
            int d = c - 64;
            size_t base = ((size_t)bh * HDIM + d) * TC2 + t;
            vtb[base + 0 * TC2] = f2bf(val.x); vtb[base + 1 * TC2] = f2bf(val.y);
            vtb[base + 2 * TC2] = f2bf(val.z); vtb[base + 3 * TC2] = f2bf(val.w);
        }
    }
}

// ---------------------------------------------------------------------------
// 128x128 GEMM, BK=64, global_load_lds staging (unchanged).
// ---------------------------------------------------------------------------
__global__ __launch_bounds__(256) void gemm128(
    const short* __restrict__ A0, const short* __restrict__ A1, const short* __restrict__ A2,
    const short* __restrict__ W0, const short* __restrict__ W1, const short* __restrict__ W2,
    const float* __restrict__ b0, const float* __restrict__ b1, const float* __restrict__ b2,
    float* __restrict__ outf, short* __restrict__ qbuf,
    short* __restrict__ kbb, short* __restrict__ vtb, int base_mode)
{
    __shared__ short As[128 * 64];
    __shared__ short Bs[128 * 64];

    int mode;
    const short *A, *W;
    const float* bias;
    if (base_mode == 3) { mode = 3; A = A0; W = W0; bias = b0; }
    else {
        mode = blockIdx.z;
        if (mode == 0)      { A = A0; W = W0; bias = b0; }
        else if (mode == 1) { A = A1; W = W1; bias = b1; }
        else                { A = A2; W = W2; bias = b2; }
    }

    const int tid = threadIdx.x, lane = tid & 63, w = tid >> 6;
    const int wr = w >> 1, wc = w & 1;
    const int lr = lane & 15, lg = lane >> 4;
    const int bx = blockIdx.x, by = blockIdx.y;

    f32x4 acc[4][4];
#pragma unroll
    for (int m = 0; m < 4; ++m)
#pragma unroll
        for (int n = 0; n < 4; ++n) acc[m][n] = (f32x4){0.f, 0.f, 0.f, 0.f};

    const short* agBase = A + (size_t)(by * 128 + w * 32 + (lane >> 3)) * 1024 + (lane & 7) * 8;
    const short* bgBase = W + (size_t)(bx * 128 + w * 32 + (lane >> 3)) * 1024 + (lane & 7) * 8;
    short* asW = &As[w * 2048];
    short* bsW = &Bs[w * 2048];

    for (int kt = 0; kt < 16; ++kt) {
        const short* ag = agBase + kt * 64;
        const short* bg = bgBase + kt * 64;
        GLOAD16(ag,          asW);
        GLOAD16(ag + 8192,   asW + 512);
        GLOAD16(ag + 16384,  asW + 1024);
        GLOAD16(ag + 24576,  asW + 1536);
        GLOAD16(bg,          bsW);
        GLOAD16(bg + 8192,   bsW + 512);
        GLOAD16(bg + 16384,  bsW + 1024);
        GLOAD16(bg + 24576,  bsW + 1536);
        __syncthreads();
#pragma unroll
        for (int kk = 0; kk < 2; ++kk) {
            short8 af[4], bf[4];
#pragma unroll
            for (int m = 0; m < 4; ++m)
                af[m] = *(const short8*)&As[(wr * 64 + m * 16 + lr) * 64 + kk * 32 + lg * 8];
#pragma unroll
            for (int n = 0; n < 4; ++n)
                bf[n] = *(const short8*)&Bs[(wc * 64 + n * 16 + lr) * 64 + kk * 32 + lg * 8];
#pragma unroll
            for (int m = 0; m < 4; ++m)
#pragma unroll
                for (int n = 0; n < 4; ++n)
                    acc[m][n] = mfma_bf16(af[m], bf[n], acc[m][n]);
        }
        __syncthreads();
    }

#pragma unroll
    for (int m = 0; m < 4; ++m) {
#pragma unroll
        for (int n = 0; n < 4; ++n) {
            const int cg = bx * 128 + wc * 64 + n * 16 + lr;
            const int rg0 = by * 128 + wr * 64 + m * 16 + lg * 4;
            const float bv = bias[cg];
            if (mode == 3) {
#pragma unroll
                for (int r = 0; r < 4; ++r)
                    outf[(size_t)(rg0 + r) * NFEAT + cg] = acc[m][n][r] + bv;
            } else {
                const int b = rg0 >> 10, t0 = rg0 & 1023;
                const int h = cg >> 6, d = cg & 63;
                const size_t bh = (size_t)b * NHEAD + h;
                if (mode == 0) {
#pragma unroll
                    for (int r = 0; r < 4; ++r)
                        qbuf[(bh * 1024 + t0 + r) * HDIM + d] = f2bf((acc[m][n][r] + bv) * QSCL);
                } else if (mode == 1) {
#pragma unroll
                    for (int r = 0; r < 4; ++r) {
                        float val = acc[m][n][r] + bv;
                        outf[(bh * TC2 + 1024 + t0 + r) * 128 + d] = val;
                        kbb[(bh * TC2 + 1024 + t0 + r) * HDIM + d] = f2bf(val);
                    }
                } else {
                    short4s pk;
#pragma unroll
                    for (int r = 0; r < 4; ++r) {
                        float val = acc[m][n][r] + bv;
                        outf[(bh * TC2 + 1024 + t0 + r) * 128 + 64 + d] = val;
                        pk[r] = f2bf(val);
                    }
                    *(short4s*)&vtb[(bh * HDIM + d) * TC2 + 1024 + t0] = pk;
                }
            }
        }
    }
}

// ---------------------------------------------------------------------------
// Flash attention v5: 8 waves/block (512 thr), QBLK=128 (wave = 16 q-rows),
// KV-split 4 (each block does 512 kv in 8 iters of 64). Swapped QK^T softmax,
// async double-buffered global_load_lds staging (swizzled source), defer-max.
// LDS: K dbuf 16K + V dbuf 16K + P 16K = 48KB -> 3 blocks/CU (24 waves/CU).
// Grid 1024 = xcd(8) x unit16(16) x qt(8); unit = (bh,quarter).
// ---------------------------------------------------------------------------
__global__ __launch_bounds__(512) void attn_kernel(
    const short* __restrict__ qb, const short* __restrict__ kb,
    const short* __restrict__ vtb, short* __restrict__ opart, float* __restrict__ mlbuf)
{
    __shared__ short Ks[2][64 * 64];
    __shared__ short Vs[2][64 * 64];
    __shared__ short Ps[8][16 * 64];

    const int tid = threadIdx.x, lane = tid & 63, w = tid >> 6;
    const int lr = lane & 15, lg = lane >> 4;
    const int b0 = blockIdx.x;
    const int xcd = b0 & 7, rest = b0 >> 3;           // 8 x 128
    const int unit = xcd + 8 * (rest & 15);           // 0..127 = bh*4 + quarter
    const int qt = rest >> 4;                         // 0..7
    const int bh = unit >> 2, quarter = unit & 3;
    const int xz = lr & 7;

    // Q fragment (B operand): q-row = lr within wave's 16 rows
    const short* qrow = qb + ((size_t)bh * 1024 + qt * 128 + w * 16 + lr) * HDIM + lg * 8;
    const short8 bq0 = *(const short8*)(qrow);
    const short8 bq1 = *(const short8*)(qrow + 32);

    // staging: 512 threads cover one 64x64 bf16 tile with one 16B load each.
    // source column pre-swizzled so linear LDS holds swizzled data (rule 21).
    const int srow = tid >> 3;                        // 0..63 (wave w -> rows w*8..w*8+7)
    const int scx = ((tid & 7) ^ (srow & 7)) * 8;
    const short* kgb = kb  + ((size_t)bh * TC2 + quarter * 512 + srow) * HDIM + scx;
    const short* vgb = vtb + ((size_t)bh * HDIM + srow) * TC2 + quarter * 512 + scx;
    short* kdst = &Ks[0][0] + w * 512;                // wave-uniform base (+4096 buf1)
    short* vdst = &Vs[0][0] + w * 512;

#define STAGE(bufsel, kvt_) do {                                         \
        const short* kg_ = kgb + (size_t)(kvt_) * 64 * HDIM;             \
        const short* vg_ = vgb + (kvt_) * 64;                            \
        GLOAD16(kg_, kdst + (bufsel) * 4096);                            \
        GLOAD16(vg_, vdst + (bufsel) * 4096);                            \
    } while (0)

    f32x4 accx[4];
#pragma unroll
    for (int i = 0; i < 4; ++i) accx[i] = (f32x4){0.f, 0.f, 0.f, 0.f};
    float ms = -3.0e38f, ls = 0.f;
    short* pw = &Ps[w][0];

    STAGE(0, 0);
    __syncthreads();

    int cur = 0;
    for (int kvt = 0; kvt < 8; ++kvt) {
        if (kvt < 7) STAGE(cur ^ 1, kvt + 1);
        const short* Kc = &Ks[cur][0];
        const short* Vc = &Vs[cur][0];

        // ---- S^T = K Q^T  (lane: q-row = lr; kv = 16n + 4lg + r) ----
        f32x4 s[4];
#pragma unroll
        for (int n = 0; n < 4; ++n) {
            const short* kt = Kc + (n * 16 + lr) * 64;
            short8 k0 = *(const short8*)&kt[(lg ^ xz) * 8];
            short8 k1 = *(const short8*)&kt[((4 + lg) ^ xz) * 8];
            s[n] = (f32x4){0.f, 0.f, 0.f, 0.f};
            s[n] = mfma_bf16(k0, bq0, s[n]);
            s[n] = mfma_bf16(k1, bq1, s[n]);
        }

        // ---- row max (in-register tree + 2 shuffles) ----
        float v8[8];
#pragma unroll
        for (int i = 0; i < 8; ++i) v8[i] = fmaxf(s[i >> 1][(i & 1) * 2], s[i >> 1][(i & 1) * 2 + 1]);
        float v4a = fmaxf(v8[0], v8[1]), v4b = fmaxf(v8[2], v8[3]);
        float v4c = fmaxf(v8[4], v8[5]), v4d = fmaxf(v8[6], v8[7]);
        float pmax = fmaxf(fmaxf(v4a, v4b), fmaxf(v4c, v4d));
        pmax = fmaxf(pmax, __shfl_xor(pmax, 16));
        pmax = fmaxf(pmax, __shfl_xor(pmax, 32));

        // ---- defer-max rescale (T13) ----
        if (!__all(pmax - ms <= 8.0f)) {
            float mn = fmaxf(ms, pmax);
            float alpha = __builtin_amdgcn_exp2f(ms - mn);
            ms = mn;
            ls *= alpha;
            float ar[4];
#pragma unroll
            for (int r = 0; r < 4; ++r) ar[r] = __shfl(alpha, lg * 4 + r);
#pragma unroll
            for (int nd = 0; nd < 4; ++nd)
#pragma unroll
                for (int r = 0; r < 4; ++r) accx[nd][r] *= ar[r];
        }

        // ---- P = exp2(S - m), row sum ----
        float p[4][4];
        float sm[8];
#pragma unroll
        for (int n = 0; n < 4; ++n)
#pragma unroll
            for (int r = 0; r < 4; ++r) p[n][r] = __builtin_amdgcn_exp2f(s[n][r] - ms);
#pragma unroll
        for (int i = 0; i < 8; ++i) sm[i] = p[i >> 1][(i & 1) * 2] + p[i >> 1][(i & 1) * 2 + 1];
        float rs = ((sm[0] + sm[1]) + (sm[2] + sm[3])) + ((sm[4] + sm[5]) + (sm[6] + sm[7]));
        rs += __shfl_xor(rs, 16);
        rs += __shfl_xor(rs, 32);
        ls += rs;

        // ---- pack P -> wave-private swizzled LDS [16 q-rows][64 kv] ----
#pragma unroll
        for (int n = 0; n < 4; ++n) {
            short4s pk;
            pk[0] = f2bfq(p[n][0]); pk[1] = f2bfq(p[n][1]);
            pk[2] = f2bfq(p[n][2]); pk[3] = f2bfq(p[n][3]);
            int slot = (2 * n + (lg >> 1)) ^ xz;
            *(short4s*)&pw[lr * 64 + slot * 8 + (lg & 1) * 4] = pk;
        }

        // ---- PV: O += P V ----
        short8 ap0 = *(const short8*)&pw[lr * 64 + (lg ^ xz) * 8];
        short8 ap1 = *(const short8*)&pw[lr * 64 + ((4 + lg) ^ xz) * 8];
#pragma unroll
        for (int nd = 0; nd < 4; ++nd) {
            const short* vt = Vc + (nd * 16 + lr) * 64;
            short8 vf0 = *(const short8*)&vt[(lg ^ xz) * 8];
            short8 vf1 = *(const short8*)&vt[((4 + lg) ^ xz) * 8];
            accx[nd] = mfma_bf16(ap0, vf0, accx[nd]);
            accx[nd] = mfma_bf16(ap1, vf1, accx[nd]);
        }

        __syncthreads();     // implicit vmcnt(0): next tile staged; buf reuse safe
        cur ^= 1;
    }

    // ---- epilogue: bf16 partials + (m,l) ----
    const size_t rbase = (size_t)quarter * 32768 + (size_t)bh * 1024 + qt * 128 + w * 16;
#pragma unroll
    for (int nd = 0; nd < 4; ++nd)
#pragma unroll
        for (int r = 0; r < 4; ++r)
            opart[(rbase + lg * 4 + r) * 64 + nd * 16 + lr] = f2bfq(accx[nd][r]);
    if (lg == 0) {
        mlbuf[(rbase + lr) * 2]     = ms;
        mlbuf[(rbase + lr) * 2 + 1] = ls;
    }
#undef STAGE
}

// ---------------------------------------------------------------------------
// Combine the four kv-quarters: out = sum_i O_i*2^(m_i-M) / sum_i l_i*2^(m_i-M)
// ---------------------------------------------------------------------------
__global__ __launch_bounds__(256) void combine_kernel(
    const short* __restrict__ opart, const float* __restrict__ mlbuf,
    short* __restrict__ xb)
{
    int idx = blockIdx.x * 256 + threadIdx.x;    // 262144 = 32768 rows x 8 segs
    int r = idx >> 3, d8 = (idx & 7) * 8;
    float m[4], l[4];
#pragma unroll
    for (int i = 0; i < 4; ++i) {
        m[i] = mlbuf[((size_t)i * 32768 + r) * 2];
        l[i] = mlbuf[((size_t)i * 32768 + r) * 2 + 1];
    }
    float M = fmaxf(fmaxf(m[0], m[1]), fmaxf(m[2], m[3]));
    float acc[8];
#pragma unroll
    for (int j = 0; j < 8; ++j) acc[j] = 0.f;
    float lsum = 0.f;
#pragma unroll
    for (int i = 0; i < 4; ++i) {
        float wi = __builtin_amdgcn_exp2f(m[i] - M);
        lsum += l[i] * wi;
        short8 op = *(const short8*)&opart[((size_t)i * 32768 + r) * 64 + d8];
#pragma unroll
        for (int j = 0; j < 8; ++j) acc[j] += bf2f(op[j]) * wi;
    }
    float inv = 1.0f / lsum;
    short8 o;
#pragma unroll
    for (int j = 0; j < 8; ++j) o[j] = f2bfq(acc[j] * inv);
    int bh = r >> 10, tq = r & 1023;
    int b = bh >> 4, h = bh & 15;
    *(short8*)&xb[((size_t)(b * 1024 + tq)) * NFEAT + h * 64 + d8] = o;
}

// ---------------------------------------------------------------------------
extern "C" void kernel_launch(void* const* d_in, const int* in_sizes, int n_in,
                              void* d_out, int out_size, void* d_ws, size_t ws_size,
                              hipStream_t stream) {
    const float* query = (const float*)d_in[0];
    const float* key   = (const float*)d_in[1];
    const float* value = (const float*)d_in[2];
    const float* cache = (const float*)d_in[3];
    const float* Wq = (const float*)d_in[4];
    const float* bq = (const float*)d_in[5];
    const float* Wk = (const float*)d_in[6];
    const float* bk = (const float*)d_in[7];
    const float* Wv = (const float*)d_in[8];
    const float* bv = (const float*)d_in[9];
    const float* Wo = (const float*)d_in[10];
    const float* bo = (const float*)d_in[11];

    float* out0   = (float*)d_out;
    float* ncache = out0 + (size_t)2 * 1024 * 1024;

    short* qin = (short*)d_ws;                       // 0      (2M shorts)
    short* kin = qin + (size_t)2097152;              // 2M
    short* vin = kin + (size_t)2097152;              // 4M
    short* wqb = vin + (size_t)2097152;              // 6M
    short* wkb = wqb + (size_t)1048576;              // 7M
    short* wvb = wkb + (size_t)1048576;              // 8M
    short* wob = wvb + (size_t)1048576;              // 9M
    short* qbuf = wob + (size_t)1048576;             // 10M (2M)
    short* kbb  = qbuf + (size_t)2097152;            // 12M (4M)
    short* vtb  = kbb  + (size_t)4194304;            // 16M (4M) -> 20M total
    // Overlays (regions dead by the time attn runs):
    short* opart = (short*)d_ws;                     // [4][32768][64] bf16 = 8,388,608 shorts (qin..wkb)
    float* mlbuf = (float*)(qin + (size_t)8388608);  // [4][32768][2] f32 = 524,288 shorts (wvb region)
    short* xb    = qbuf;                             // combine output (Q dead then)

    prep_kernel<<<9216, 256, 0, stream>>>(query, key, value, Wq, Wk, Wv, Wo,
        (const float4*)cache, qin, kin, vin, wqb, wkb, wvb, wob,
        (float4*)ncache, kbb, vtb);

    gemm128<<<dim3(8, 16, 3), 256, 0, stream>>>(qin, kin, vin, wqb, wkb, wvb,
        bq, bk, bv, ncache, qbuf, kbb, vtb, 0);

    attn_kernel<<<1024, 512, 0, stream>>>(qbuf, kbb, vtb, opart, mlbuf);

    combine_kernel<<<1024, 256, 0, stream>>>(opart, mlbuf, xb);

    gemm128<<<dim3(8, 16, 1), 256, 0, stream>>>(xb, nullptr, nullptr, wob, nullptr, nullptr,
        bo, nullptr, nullptr, out0, nullptr, nullptr, nullptr, 3);
}